// Round 9
// baseline (180.651 us; speedup 1.0000x reference)
//
#include <hip/hip_runtime.h>
#include <hip/hip_bf16.h>

// SimpleMetaConvKALN: x (64,64,64,64) f32, w (32,80,3,3) f32 -> out (64,128,64,64) f32
// y = conv3x3(aug(x), w) per group; instance-norm per (b,oc); silu.
// K=64 (ones-block analytic via T[oc][ey][ex]).
// Persistent block per (b,g): weights in LDS once, 16 spatial tiles pipelined
// with double-buffered aug (stage t+1 overlaps MFMA t), dual accumulators.

#define NB 64
#define NH 64
#define NW 64

typedef __attribute__((ext_vector_type(8)))  short bf16x8;
typedef __attribute__((ext_vector_type(16))) float f32x16;

#define WLDS_BYTES 36864              // 9*8*32*8*2
#define AUG_BYTES  41472              // 8*324*8*2
#define TL_BYTES   1152               // 288*4
#define SMEM_BYTES (WLDS_BYTES + 2 * AUG_BYTES + TL_BYTES)   // 120960

__device__ __forceinline__ float silu(float v) {
    return v / (1.0f + __expf(-v));
}
__device__ __forceinline__ unsigned short tobf(float f) {   // native cvt (RNE)
    union { __hip_bfloat16 h; unsigned short u; } cv;
    cv.h = __float2bfloat16(f);
    return cv.u;
}

// ---- per-plane min/max (no atomics) ----
__global__ __launch_bounds__(256) void minmax_kernel(const float* __restrict__ x,
                                                     float* __restrict__ pmm) {
    int plane = blockIdx.x;          // b*64 + ch
    const float4* p = (const float4*)(x + (size_t)plane * 4096);
    int t = threadIdx.x;
    float mn = 3.4e38f, mx = -3.4e38f;
    #pragma unroll
    for (int k = 0; k < 4; ++k) {
        float4 v = p[t + k * 256];
        mn = fminf(mn, fminf(fminf(v.x, v.y), fminf(v.z, v.w)));
        mx = fmaxf(mx, fmaxf(fmaxf(v.x, v.y), fmaxf(v.z, v.w)));
    }
    #pragma unroll
    for (int off = 32; off; off >>= 1) {
        mn = fminf(mn, __shfl_xor(mn, off));
        mx = fmaxf(mx, __shfl_xor(mx, off));
    }
    __shared__ float smn[4], smx[4];
    int wid = t >> 6, lane = t & 63;
    if (lane == 0) { smn[wid] = mn; smx[wid] = mx; }
    __syncthreads();
    if (t == 0) {
        mn = fminf(fminf(smn[0], smn[1]), fminf(smn[2], smn[3]));
        mx = fmaxf(fmaxf(smx[0], smx[1]), fmaxf(smx[2], smx[3]));
        pmm[plane * 2]     = mn;
        pmm[plane * 2 + 1] = mx;
    }
}

// blk 0-3: reduce pmm -> wsf[g]; blk 4-75: repack w -> bf16 [tap][kq][oc][8];
// blk 76: ones-channel analytic table T[oc][ey][ex]
__global__ __launch_bounds__(256) void reduce_repack_kernel(const float* __restrict__ pmm,
                                                            const float* __restrict__ w,
                                                            float* __restrict__ wsf,
                                                            unsigned short* __restrict__ wpk,
                                                            float* __restrict__ Tt) {
    int blk = blockIdx.x;
    int t = threadIdx.x;
    if (blk < 4) {
        int g = blk;
        float mn = 3.4e38f, mx = -3.4e38f;
        #pragma unroll
        for (int j = 0; j < 4; ++j) {
            int p = t + j * 256;             // 0..1023
            int b = p >> 4, c = p & 15;
            int plane = b * 64 + g * 16 + c;
            mn = fminf(mn, pmm[plane * 2]);
            mx = fmaxf(mx, pmm[plane * 2 + 1]);
        }
        #pragma unroll
        for (int off = 32; off; off >>= 1) {
            mn = fminf(mn, __shfl_xor(mn, off));
            mx = fmaxf(mx, __shfl_xor(mx, off));
        }
        __shared__ float smn[4], smx[4];
        int wid = t >> 6, lane = t & 63;
        if (lane == 0) { smn[wid] = mn; smx[wid] = mx; }
        __syncthreads();
        if (t == 0) {
            mn = fminf(fminf(smn[0], smn[1]), fminf(smn[2], smn[3]));
            mx = fmaxf(fmaxf(smx[0], smx[1]), fmaxf(smx[2], smx[3]));
            wsf[g * 2]     = mn;
            wsf[g * 2 + 1] = mx;
        }
    } else if (blk < 76) {
        int idx = (blk - 4) * 256 + t;       // < 18432 = 9*8*32*8
        int tap = idx / 2048;
        int r   = idx - tap * 2048;
        int kq  = r >> 8;                    // 0..7 (8-wide k chunk)
        int oc  = (r >> 3) & 31;
        int j   = r & 7;
        int k   = kq * 8 + j;
        int orig = (k < 16) ? k : (k + 16);  // skip ones block (orig 16..31)
        wpk[idx] = tobf(w[oc * 720 + orig * 9 + tap]);
    } else {
        for (int i = t; i < 288; i += 256) {
            int oc = i / 9, ty = i - oc * 9;
            int ey = ty / 3, ex = ty - ey * 3;
            int ky0 = (ey == 0) ? 1 : 0, ky1 = (ey == 2) ? 1 : 2;
            int kx0 = (ex == 0) ? 1 : 0, kx1 = (ex == 2) ? 1 : 2;
            float s = 0.f;
            for (int c = 0; c < 16; ++c)
                for (int ky = ky0; ky <= ky1; ++ky)
                    for (int kx = kx0; kx <= kx1; ++kx)
                        s += w[oc * 720 + (16 + c) * 9 + ky * 3 + kx];
            Tt[i] = s;
        }
    }
}

// ---- staging helpers: 648 tasks = 324 halo px x 2 channel-halves ----
// task loads 8 floats, writes 4 b128 chunks: {half, 2+half, 4+half, 6+half}
__device__ __forceinline__ void stage_load(const float* __restrict__ xg, int tile,
                                           int t, float r[2][8], bool okv[2]) {
    int th0 = (tile >> 2) * 16, tw0 = (tile & 3) * 16;
    #pragma unroll
    for (int i = 0; i < 2; ++i) {
        int idx = t + i * 512;
        if (idx < 648) {
            int half = idx >= 324 ? 1 : 0;
            int pix = idx - half * 324;
            int ly = pix / 18, lx = pix - ly * 18;
            int gh = th0 + ly - 1, gw = tw0 + lx - 1;
            bool ok = (gh >= 0 && gh < NH && gw >= 0 && gw < NW);
            okv[i] = ok;
            const float* s = xg + (size_t)(half * 8) * 4096 + gh * 64 + gw;
            #pragma unroll
            for (int j = 0; j < 8; ++j)
                r[i][j] = ok ? s[(size_t)j * 4096] : 0.f;
        }
    }
}

__device__ __forceinline__ void stage_write(unsigned short* __restrict__ buf, int t,
                                            const float r[2][8], const bool okv[2],
                                            float xmin, float inv) {
    #pragma unroll
    for (int i = 0; i < 2; ++i) {
        int idx = t + i * 512;
        if (idx < 648) {
            int half = idx >= 324 ? 1 : 0;
            int pix = idx - half * 324;
            bool ok = okv[i];
            bf16x8 vs, v1, v2, v3;
            #pragma unroll
            for (int j = 0; j < 8; ++j) {
                float val = r[i][j];
                vs[j] = (short)tobf(silu(val));
                float xn = (val - xmin) * inv - 1.f;
                float p2 = 1.5f * xn * xn - 0.5f;
                float p3 = (2.5f * xn * xn - 1.5f) * xn;
                v1[j] = ok ? (short)tobf(xn) : (short)0;
                v2[j] = ok ? (short)tobf(p2) : (short)0;
                v3[j] = ok ? (short)tobf(p3) : (short)0;
            }
            *(bf16x8*)&buf[((0 + half) * 324 + pix) * 8] = vs;
            *(bf16x8*)&buf[((2 + half) * 324 + pix) * 8] = v1;
            *(bf16x8*)&buf[((4 + half) * 324 + pix) * 8] = v2;
            *(bf16x8*)&buf[((6 + half) * 324 + pix) * 8] = v3;
        }
    }
}

__global__ __launch_bounds__(512, 2) void conv_mfma_kernel(const float* __restrict__ x,
                                                           const float* __restrict__ wsf,
                                                           const unsigned short* __restrict__ wpk,
                                                           const float* __restrict__ Tt,
                                                           float* __restrict__ out) {
    extern __shared__ char smem[];
    unsigned short* wl   = (unsigned short*)smem;                         // [tap][kq][oc][8]
    unsigned short* augA = (unsigned short*)(smem + WLDS_BYTES);
    unsigned short* augB = (unsigned short*)(smem + WLDS_BYTES + AUG_BYTES);
    float*          Tl   = (float*)(smem + WLDS_BYTES + 2 * AUG_BYTES);   // 288 floats

    int f = blockIdx.x;            // 0..255 : one block per (b,g)
    int b = f >> 2, g = f & 3;

    float xmin = wsf[g * 2];
    float xmax = wsf[g * 2 + 1];
    float inv = 2.0f / (xmax - xmin);

    const float* xg = x + ((size_t)b * 64 + g * 16) * 4096;
    int t = threadIdx.x;

    // ---- weight table + T: global -> LDS once per block ----
    {
        const uint4* src = (const uint4*)wpk;
        uint4* dst = (uint4*)wl;
        #pragma unroll
        for (int i = 0; i < 5; ++i) {
            int idx = t + i * 512;
            if (idx < 2304) dst[idx] = src[idx];
        }
    }
    if (t < 288) Tl[t] = Tt[t];

    int wv = t >> 6;
    int lane = t & 63;
    int lo = lane & 31, hi = lane >> 5;
    int py = 2 * wv + (lo >> 4), px = lo & 15;

    // ---- prologue: stage tile 0 into augA ----
    {
        float r[2][8]; bool okv[2];
        stage_load(xg, 0, t, r, okv);
        stage_write(augA, t, r, okv, xmin, inv);
    }
    __syncthreads();

    size_t gbase = ((size_t)b * 128 + g * 32) * 4096;

    for (int tile = 0; tile < 16; ++tile) {
        unsigned short* cur = (tile & 1) ? augB : augA;
        unsigned short* nxt = (tile & 1) ? augA : augB;

        // issue next tile's global loads first (latency hides under MFMA)
        float r[2][8]; bool okv[2];
        if (tile < 15) stage_load(xg, tile + 1, t, r, okv);

        // ---- MFMA: dual accumulators split the dependency chain ----
        f32x16 acc0 = {}, acc1 = {};
        #pragma unroll
        for (int tap = 0; tap < 9; ++tap) {
            const int ky = tap / 3, kx = tap % 3;
            const int hp = (py + ky) * 18 + (px + kx);
            #pragma unroll
            for (int kcg = 0; kcg < 4; ++kcg) {
                bf16x8 Af = *(const bf16x8*)&wl[((tap * 8 + kcg * 2 + hi) * 32 + lo) * 8];
                bf16x8 Bf = *(const bf16x8*)&cur[(((kcg * 2 + hi) * 324) + hp) * 8];
                if (tap & 1)
                    acc1 = __builtin_amdgcn_mfma_f32_32x32x16_bf16(Af, Bf, acc1, 0, 0, 0);
                else
                    acc0 = __builtin_amdgcn_mfma_f32_32x32x16_bf16(Af, Bf, acc0, 0, 0, 0);
            }
        }

        // transform + write next tile to the other buffer
        if (tile < 15) stage_write(nxt, t, r, okv, xmin, inv);

        // ---- epilogue: ones-term + direct coalesced stores ----
        int th0 = (tile >> 2) * 16, tw0 = (tile & 3) * 16;
        int h = th0 + py, wc = tw0 + px;
        int ey = (h == 0) ? 0 : ((h == NH - 1) ? 2 : 1);
        int ex = (wc == 0) ? 0 : ((wc == NW - 1) ? 2 : 1);
        int et = ey * 3 + ex;
        size_t obase = gbase + (size_t)h * 64 + wc;
        #pragma unroll
        for (int rr = 0; rr < 16; ++rr) {
            int oc = (rr & 3) + 8 * (rr >> 2) + 4 * hi;
            out[obase + (size_t)oc * 4096] = acc0[rr] + acc1[rr] + Tl[oc * 9 + et];
        }

        __syncthreads();   // nxt fully written & cur reads done before swap
    }
}

__global__ __launch_bounds__(256) void norm_kernel(float* __restrict__ out) {
    int plane = blockIdx.x;      // b*128 + ch
    float4* p = (float4*)(out + (size_t)plane * 4096);
    int t = threadIdx.x;
    float4 v[4];
    float s = 0.f, s2 = 0.f;
    #pragma unroll
    for (int k = 0; k < 4; ++k) {
        v[k] = p[t + k * 256];
        s  += v[k].x + v[k].y + v[k].z + v[k].w;
        s2 += v[k].x * v[k].x + v[k].y * v[k].y + v[k].z * v[k].z + v[k].w * v[k].w;
    }
    #pragma unroll
    for (int off = 32; off; off >>= 1) {
        s  += __shfl_xor(s, off);
        s2 += __shfl_xor(s2, off);
    }
    __shared__ float ss[4], ss2[4];
    int wid = t >> 6, lane = t & 63;
    if (lane == 0) { ss[wid] = s; ss2[wid] = s2; }
    __syncthreads();
    s  = ss[0] + ss[1] + ss[2] + ss[3];
    s2 = ss2[0] + ss2[1] + ss2[2] + ss2[3];
    float mean = s * (1.f / 4096.f);
    float var  = fmaxf(s2 * (1.f / 4096.f) - mean * mean, 0.f);
    float istd = rsqrtf(var + 1e-5f);
    #pragma unroll
    for (int k = 0; k < 4; ++k) {
        float4 o;
        o.x = (v[k].x - mean) * istd; o.x = silu(o.x);
        o.y = (v[k].y - mean) * istd; o.y = silu(o.y);
        o.z = (v[k].z - mean) * istd; o.z = silu(o.z);
        o.w = (v[k].w - mean) * istd; o.w = silu(o.w);
        p[t + k * 256] = o;
    }
}

extern "C" void kernel_launch(void* const* d_in, const int* in_sizes, int n_in,
                              void* d_out, int out_size, void* d_ws, size_t ws_size,
                              hipStream_t stream) {
    const float* x = (const float*)d_in[0];
    const float* w = (const float*)d_in[1];
    float* out = (float*)d_out;
    float* wsf = (float*)d_ws;                                        // 8 floats
    float* pmm = (float*)((char*)d_ws + 64);                          // 8192 floats
    unsigned short* wpk = (unsigned short*)((char*)d_ws + 64 + 32768);// 18432 bf16
    float* Tt = (float*)((char*)d_ws + 64 + 32768 + 36864);           // 288 floats

    static int smem_set = 0;
    if (!smem_set) {
        hipFuncSetAttribute((const void*)conv_mfma_kernel,
                            hipFuncAttributeMaxDynamicSharedMemorySize, SMEM_BYTES);
        smem_set = 1;
    }

    hipLaunchKernelGGL(minmax_kernel, dim3(NB * 64), dim3(256), 0, stream, x, pmm);
    hipLaunchKernelGGL(reduce_repack_kernel, dim3(77), dim3(256), 0, stream, pmm, w, wsf, wpk, Tt);
    hipLaunchKernelGGL(conv_mfma_kernel, dim3(256), dim3(512), SMEM_BYTES, stream, x, wsf, wpk, Tt, out);
    hipLaunchKernelGGL(norm_kernel, dim3(NB * 128), dim3(256), 0, stream, out);
}

// Round 10
// 139.368 us; speedup vs baseline: 1.2962x; 1.2962x over previous
//
#include <hip/hip_runtime.h>
#include <hip/hip_bf16.h>

// SimpleMetaConvKALN: x (64,64,64,64) f32, w (32,80,3,3) f32 -> out (64,128,64,64) f32
// y = conv3x3(aug(x), w) per group; instance-norm per (b,oc); silu.
// K=64 (ones-block analytic via T[oc][ey][ex]).
// K processed in 4 phases (silu / xn / P2 / P3): x tile held in registers,
// per-phase aug (2 chunks, 10.4KB) + per-phase weights (9.2KB) in LDS
// -> 20.7KB LDS/block -> 3-4 blocks/CU.  One MFMA per tap per phase.

#define NB 64
#define NH 64
#define NW 64

typedef __attribute__((ext_vector_type(8)))  short bf16x8;
typedef __attribute__((ext_vector_type(16))) float f32x16;

__device__ __forceinline__ float silu(float v) {
    return v / (1.0f + __expf(-v));
}
__device__ __forceinline__ unsigned short tobf(float f) {   // native cvt (RNE)
    union { __hip_bfloat16 h; unsigned short u; } cv;
    cv.h = __float2bfloat16(f);
    return cv.u;
}

// ---- per-plane min/max (no atomics) ----
__global__ __launch_bounds__(256) void minmax_kernel(const float* __restrict__ x,
                                                     float* __restrict__ pmm) {
    int plane = blockIdx.x;          // b*64 + ch
    const float4* p = (const float4*)(x + (size_t)plane * 4096);
    int t = threadIdx.x;
    float mn = 3.4e38f, mx = -3.4e38f;
    #pragma unroll
    for (int k = 0; k < 4; ++k) {
        float4 v = p[t + k * 256];
        mn = fminf(mn, fminf(fminf(v.x, v.y), fminf(v.z, v.w)));
        mx = fmaxf(mx, fmaxf(fmaxf(v.x, v.y), fmaxf(v.z, v.w)));
    }
    #pragma unroll
    for (int off = 32; off; off >>= 1) {
        mn = fminf(mn, __shfl_xor(mn, off));
        mx = fmaxf(mx, __shfl_xor(mx, off));
    }
    __shared__ float smn[4], smx[4];
    int wid = t >> 6, lane = t & 63;
    if (lane == 0) { smn[wid] = mn; smx[wid] = mx; }
    __syncthreads();
    if (t == 0) {
        mn = fminf(fminf(smn[0], smn[1]), fminf(smn[2], smn[3]));
        mx = fmaxf(fmaxf(smx[0], smx[1]), fmaxf(smx[2], smx[3]));
        pmm[plane * 2]     = mn;
        pmm[plane * 2 + 1] = mx;
    }
}

// blk 0-3: reduce pmm -> wsf[g]
// blk 4-75: repack w -> bf16 phase-major [p][tap][h][oc][8]
// blk 76: ones-channel analytic table T[oc][ey][ex]
__global__ __launch_bounds__(256) void reduce_repack_kernel(const float* __restrict__ pmm,
                                                            const float* __restrict__ w,
                                                            float* __restrict__ wsf,
                                                            unsigned short* __restrict__ wpk,
                                                            float* __restrict__ Tt) {
    int blk = blockIdx.x;
    int t = threadIdx.x;
    if (blk < 4) {
        int g = blk;
        float mn = 3.4e38f, mx = -3.4e38f;
        #pragma unroll
        for (int j = 0; j < 4; ++j) {
            int p = t + j * 256;             // 0..1023
            int b = p >> 4, c = p & 15;
            int plane = b * 64 + g * 16 + c;
            mn = fminf(mn, pmm[plane * 2]);
            mx = fmaxf(mx, pmm[plane * 2 + 1]);
        }
        #pragma unroll
        for (int off = 32; off; off >>= 1) {
            mn = fminf(mn, __shfl_xor(mn, off));
            mx = fmaxf(mx, __shfl_xor(mx, off));
        }
        __shared__ float smn[4], smx[4];
        int wid = t >> 6, lane = t & 63;
        if (lane == 0) { smn[wid] = mn; smx[wid] = mx; }
        __syncthreads();
        if (t == 0) {
            mn = fminf(fminf(smn[0], smn[1]), fminf(smn[2], smn[3]));
            mx = fmaxf(fmaxf(smx[0], smx[1]), fmaxf(smx[2], smx[3]));
            wsf[g * 2]     = mn;
            wsf[g * 2 + 1] = mx;
        }
    } else if (blk < 76) {
        int idx = (blk - 4) * 256 + t;       // < 18432 = 4*9*2*32*8
        int p   = idx / 4608;                // phase
        int r1  = idx - p * 4608;
        int tap = r1 / 512;
        int r2  = r1 - tap * 512;
        int h   = r2 >> 8;                   // k-half within phase
        int oc  = (r2 >> 3) & 31;
        int j   = r2 & 7;
        int k   = p * 16 + h * 8 + j;
        int orig = (k < 16) ? k : (k + 16);  // skip ones block (orig 16..31)
        wpk[idx] = tobf(w[oc * 720 + orig * 9 + tap]);
    } else {
        for (int i = t; i < 288; i += 256) {
            int oc = i / 9, ty = i - oc * 9;
            int ey = ty / 3, ex = ty - ey * 3;
            int ky0 = (ey == 0) ? 1 : 0, ky1 = (ey == 2) ? 1 : 2;
            int kx0 = (ex == 0) ? 1 : 0, kx1 = (ex == 2) ? 1 : 2;
            float s = 0.f;
            for (int c = 0; c < 16; ++c)
                for (int ky = ky0; ky <= ky1; ++ky)
                    for (int kx = kx0; kx <= kx1; ++kx)
                        s += w[oc * 720 + (16 + c) * 9 + ky * 3 + kx];
            Tt[i] = s;
        }
    }
}

__global__ __launch_bounds__(512, 6) void conv_mfma_kernel(const float* __restrict__ x,
                                                           const float* __restrict__ wsf,
                                                           const unsigned short* __restrict__ wpk,
                                                           const float* __restrict__ Tt,
                                                           float* __restrict__ out) {
    __shared__ unsigned short wlp[4608];    // [tap][h][oc][8]  9216 B
    __shared__ unsigned short augp[5184];   // [h][pix 0..323][8] 10368 B
    __shared__ float Tl[288];               // 1152 B

    // XCD swizzle: consecutive work-chunks of 512 land on one XCD
    int flat = blockIdx.x;                       // 0..4095
    int f = ((flat & 7) << 9) | (flat >> 3);     // bijective
    int tile = f & 15;
    int bg = f >> 4;
    int b = bg & 63;
    int g = bg >> 6;
    int th0 = (tile >> 2) * 16, tw0 = (tile & 3) * 16;

    float xmin = wsf[g * 2];
    float xmax = wsf[g * 2 + 1];
    float inv = 2.0f / (xmax - xmin);

    const float* xg = x + ((size_t)b * 64 + g * 16) * 4096;
    int t = threadIdx.x;
    if (t < 288) Tl[t] = Tt[t];

    // ---- load x halo tile into registers: 648 tasks = 324 px x 2 ch-halves ----
    float r[2][8];
    bool okv[2];
    #pragma unroll
    for (int i = 0; i < 2; ++i) {
        okv[i] = false;
        int idx = t + i * 512;
        if (idx < 648) {
            int half = idx >= 324 ? 1 : 0;
            int pix = idx - half * 324;
            int ly = pix / 18, lx = pix - ly * 18;
            int gh = th0 + ly - 1, gw = tw0 + lx - 1;
            bool ok = (gh >= 0 && gh < NH && gw >= 0 && gw < NW);
            okv[i] = ok;
            const float* s = xg + (size_t)(half * 8) * 4096 + gh * 64 + gw;
            #pragma unroll
            for (int j = 0; j < 8; ++j)
                r[i][j] = ok ? s[(size_t)j * 4096] : 0.f;
        }
    }

    int wv = t >> 6;
    int lane = t & 63;
    int lo = lane & 31, hi = lane >> 5;
    int py = 2 * wv + (lo >> 4), px = lo & 15;

    f32x16 acc = {};

    // ---- 4 K-phases: 0=silu, 1=xn, 2=P2, 3=P3 ----
    #pragma unroll
    for (int p = 0; p < 4; ++p) {
        // stage this phase's transform (all b128 writes)
        #pragma unroll
        for (int i = 0; i < 2; ++i) {
            int idx = t + i * 512;
            if (idx < 648) {
                int half = idx >= 324 ? 1 : 0;
                int pix = idx - half * 324;
                bf16x8 v;
                #pragma unroll
                for (int j = 0; j < 8; ++j) {
                    float val = r[i][j];
                    float o;
                    if (p == 0) {
                        o = silu(val);               // silu(0)=0: OOB safe
                    } else {
                        float xn = (val - xmin) * inv - 1.f;
                        if (p == 1) o = xn;
                        else {
                            float x2 = xn * xn;
                            o = (p == 2) ? (1.5f * x2 - 0.5f) : ((2.5f * x2 - 1.5f) * xn);
                        }
                        o = okv[i] ? o : 0.f;
                    }
                    v[j] = (short)tobf(o);
                }
                *(bf16x8*)&augp[(half * 324 + pix) * 8] = v;
            }
        }
        // copy this phase's weight slice: 9216 B = 576 uint4
        {
            const uint4* srcw = (const uint4*)(wpk + p * 4608);
            uint4* dstw = (uint4*)wlp;
            dstw[t] = srcw[t];
            int i2 = t + 512;
            if (i2 < 576) dstw[i2] = srcw[i2];
        }
        __syncthreads();

        // 9 MFMAs: one per tap (K=16 = h0/h1 halves of this phase)
        #pragma unroll
        for (int tap = 0; tap < 9; ++tap) {
            const int ky = tap / 3, kx = tap % 3;
            const int hp = (py + ky) * 18 + (px + kx);
            bf16x8 Af = *(const bf16x8*)&wlp[((tap * 2 + hi) * 32 + lo) * 8];
            bf16x8 Bf = *(const bf16x8*)&augp[(hi * 324 + hp) * 8];
            acc = __builtin_amdgcn_mfma_f32_32x32x16_bf16(Af, Bf, acc, 0, 0, 0);
        }
        __syncthreads();
    }

    // ---- epilogue: ones-term + direct coalesced stores ----
    int h = th0 + py, wc = tw0 + px;
    int ey = (h == 0) ? 0 : ((h == NH - 1) ? 2 : 1);
    int ex = (wc == 0) ? 0 : ((wc == NW - 1) ? 2 : 1);
    int et = ey * 3 + ex;
    size_t obase = ((size_t)b * 128 + g * 32) * 4096 + (size_t)h * 64 + wc;
    #pragma unroll
    for (int rr = 0; rr < 16; ++rr) {
        int oc = (rr & 3) + 8 * (rr >> 2) + 4 * hi;
        out[obase + (size_t)oc * 4096] = acc[rr] + Tl[oc * 9 + et];
    }
}

__global__ __launch_bounds__(256) void norm_kernel(float* __restrict__ out) {
    int plane = blockIdx.x;      // b*128 + ch
    float4* p = (float4*)(out + (size_t)plane * 4096);
    int t = threadIdx.x;
    float4 v[4];
    float s = 0.f, s2 = 0.f;
    #pragma unroll
    for (int k = 0; k < 4; ++k) {
        v[k] = p[t + k * 256];
        s  += v[k].x + v[k].y + v[k].z + v[k].w;
        s2 += v[k].x * v[k].x + v[k].y * v[k].y + v[k].z * v[k].z + v[k].w * v[k].w;
    }
    #pragma unroll
    for (int off = 32; off; off >>= 1) {
        s  += __shfl_xor(s, off);
        s2 += __shfl_xor(s2, off);
    }
    __shared__ float ss[4], ss2[4];
    int wid = t >> 6, lane = t & 63;
    if (lane == 0) { ss[wid] = s; ss2[wid] = s2; }
    __syncthreads();
    s  = ss[0] + ss[1] + ss[2] + ss[3];
    s2 = ss2[0] + ss2[1] + ss2[2] + ss2[3];
    float mean = s * (1.f / 4096.f);
    float var  = fmaxf(s2 * (1.f / 4096.f) - mean * mean, 0.f);
    float istd = rsqrtf(var + 1e-5f);
    #pragma unroll
    for (int k = 0; k < 4; ++k) {
        float4 o;
        o.x = (v[k].x - mean) * istd; o.x = silu(o.x);
        o.y = (v[k].y - mean) * istd; o.y = silu(o.y);
        o.z = (v[k].z - mean) * istd; o.z = silu(o.z);
        o.w = (v[k].w - mean) * istd; o.w = silu(o.w);
        p[t + k * 256] = o;
    }
}

extern "C" void kernel_launch(void* const* d_in, const int* in_sizes, int n_in,
                              void* d_out, int out_size, void* d_ws, size_t ws_size,
                              hipStream_t stream) {
    const float* x = (const float*)d_in[0];
    const float* w = (const float*)d_in[1];
    float* out = (float*)d_out;
    float* wsf = (float*)d_ws;                                        // 8 floats
    float* pmm = (float*)((char*)d_ws + 64);                          // 8192 floats
    unsigned short* wpk = (unsigned short*)((char*)d_ws + 64 + 32768);// 18432 bf16
    float* Tt = (float*)((char*)d_ws + 64 + 32768 + 36864);           // 288 floats

    hipLaunchKernelGGL(minmax_kernel, dim3(NB * 64), dim3(256), 0, stream, x, pmm);
    hipLaunchKernelGGL(reduce_repack_kernel, dim3(77), dim3(256), 0, stream, pmm, w, wsf, wpk, Tt);
    hipLaunchKernelGGL(conv_mfma_kernel, dim3(4096), dim3(512), 0, stream, x, wsf, wpk, Tt, out);
    hipLaunchKernelGGL(norm_kernel, dim3(NB * 128), dim3(256), 0, stream, out);
}

// Round 11
// 133.212 us; speedup vs baseline: 1.3561x; 1.0462x over previous
//
#include <hip/hip_runtime.h>
#include <hip/hip_bf16.h>

// SimpleMetaConvKALN: x (64,64,64,64) f32, w (32,80,3,3) f32 -> out (64,128,64,64) f32
// y = conv3x3(aug(x), w) per group; instance-norm per (b,oc); silu.
// K=64 (ones-block analytic via T[oc][ey][ex]).
// K processed in 4 phases (silu / xn / P2 / P3): x tile in registers,
// per-phase aug (10.4KB) + per-phase weights (9.2KB) in LDS -> ~21KB/block.
// y transits conv->norm as bf16 in d_ws when ws_size permits (halves norm read
// + conv write traffic); deterministic host-side fallback to f32 otherwise.

#define NB 64
#define NH 64
#define NW 64

typedef __attribute__((ext_vector_type(8)))  short bf16x8;
typedef __attribute__((ext_vector_type(8)))  unsigned short u16x8;
typedef __attribute__((ext_vector_type(16))) float f32x16;

__device__ __forceinline__ float silu(float v) {
    return v / (1.0f + __expf(-v));
}
__device__ __forceinline__ unsigned short tobf(float f) {   // native cvt (RNE)
    union { __hip_bfloat16 h; unsigned short u; } cv;
    cv.h = __float2bfloat16(f);
    return cv.u;
}

// ---- per-plane min/max (no atomics) ----
__global__ __launch_bounds__(256) void minmax_kernel(const float* __restrict__ x,
                                                     float* __restrict__ pmm) {
    int plane = blockIdx.x;          // b*64 + ch
    const float4* p = (const float4*)(x + (size_t)plane * 4096);
    int t = threadIdx.x;
    float mn = 3.4e38f, mx = -3.4e38f;
    #pragma unroll
    for (int k = 0; k < 4; ++k) {
        float4 v = p[t + k * 256];
        mn = fminf(mn, fminf(fminf(v.x, v.y), fminf(v.z, v.w)));
        mx = fmaxf(mx, fmaxf(fmaxf(v.x, v.y), fmaxf(v.z, v.w)));
    }
    #pragma unroll
    for (int off = 32; off; off >>= 1) {
        mn = fminf(mn, __shfl_xor(mn, off));
        mx = fmaxf(mx, __shfl_xor(mx, off));
    }
    __shared__ float smn[4], smx[4];
    int wid = t >> 6, lane = t & 63;
    if (lane == 0) { smn[wid] = mn; smx[wid] = mx; }
    __syncthreads();
    if (t == 0) {
        mn = fminf(fminf(smn[0], smn[1]), fminf(smn[2], smn[3]));
        mx = fmaxf(fmaxf(smx[0], smx[1]), fmaxf(smx[2], smx[3]));
        pmm[plane * 2]     = mn;
        pmm[plane * 2 + 1] = mx;
    }
}

// blk 0-3: reduce pmm -> wsf[g]
// blk 4-75: repack w -> bf16 phase-major [p][tap][h][oc][8]
// blk 76: ones-channel analytic table T[oc][ey][ex]
__global__ __launch_bounds__(256) void reduce_repack_kernel(const float* __restrict__ pmm,
                                                            const float* __restrict__ w,
                                                            float* __restrict__ wsf,
                                                            unsigned short* __restrict__ wpk,
                                                            float* __restrict__ Tt) {
    int blk = blockIdx.x;
    int t = threadIdx.x;
    if (blk < 4) {
        int g = blk;
        float mn = 3.4e38f, mx = -3.4e38f;
        #pragma unroll
        for (int j = 0; j < 4; ++j) {
            int p = t + j * 256;             // 0..1023
            int b = p >> 4, c = p & 15;
            int plane = b * 64 + g * 16 + c;
            mn = fminf(mn, pmm[plane * 2]);
            mx = fmaxf(mx, pmm[plane * 2 + 1]);
        }
        #pragma unroll
        for (int off = 32; off; off >>= 1) {
            mn = fminf(mn, __shfl_xor(mn, off));
            mx = fmaxf(mx, __shfl_xor(mx, off));
        }
        __shared__ float smn[4], smx[4];
        int wid = t >> 6, lane = t & 63;
        if (lane == 0) { smn[wid] = mn; smx[wid] = mx; }
        __syncthreads();
        if (t == 0) {
            mn = fminf(fminf(smn[0], smn[1]), fminf(smn[2], smn[3]));
            mx = fmaxf(fmaxf(smx[0], smx[1]), fmaxf(smx[2], smx[3]));
            wsf[g * 2]     = mn;
            wsf[g * 2 + 1] = mx;
        }
    } else if (blk < 76) {
        int idx = (blk - 4) * 256 + t;       // < 18432 = 4*9*2*32*8
        int p   = idx / 4608;                // phase
        int r1  = idx - p * 4608;
        int tap = r1 / 512;
        int r2  = r1 - tap * 512;
        int h   = r2 >> 8;                   // k-half within phase
        int oc  = (r2 >> 3) & 31;
        int j   = r2 & 7;
        int k   = p * 16 + h * 8 + j;
        int orig = (k < 16) ? k : (k + 16);  // skip ones block (orig 16..31)
        wpk[idx] = tobf(w[oc * 720 + orig * 9 + tap]);
    } else {
        for (int i = t; i < 288; i += 256) {
            int oc = i / 9, ty = i - oc * 9;
            int ey = ty / 3, ex = ty - ey * 3;
            int ky0 = (ey == 0) ? 1 : 0, ky1 = (ey == 2) ? 1 : 2;
            int kx0 = (ex == 0) ? 1 : 0, kx1 = (ex == 2) ? 1 : 2;
            float s = 0.f;
            for (int c = 0; c < 16; ++c)
                for (int ky = ky0; ky <= ky1; ++ky)
                    for (int kx = kx0; kx <= kx1; ++kx)
                        s += w[oc * 720 + (16 + c) * 9 + ky * 3 + kx];
            Tt[i] = s;
        }
    }
}

__global__ __launch_bounds__(512, 6) void conv_mfma_kernel(const float* __restrict__ x,
                                                           const float* __restrict__ wsf,
                                                           const unsigned short* __restrict__ wpk,
                                                           const float* __restrict__ Tt,
                                                           float* __restrict__ out,
                                                           unsigned short* __restrict__ yscr) {
    __shared__ unsigned short wlp[4608];    // [tap][h][oc][8]  9216 B
    __shared__ unsigned short augp[5184];   // [h][pix 0..323][8] 10368 B
    __shared__ float Tl[288];               // 1152 B

    // XCD swizzle: consecutive work-chunks of 512 land on one XCD
    int flat = blockIdx.x;                       // 0..4095
    int f = ((flat & 7) << 9) | (flat >> 3);     // bijective
    int tile = f & 15;
    int bg = f >> 4;
    int b = bg & 63;
    int g = bg >> 6;
    int th0 = (tile >> 2) * 16, tw0 = (tile & 3) * 16;

    float xmin = wsf[g * 2];
    float xmax = wsf[g * 2 + 1];
    float inv = 2.0f / (xmax - xmin);

    const float* xg = x + ((size_t)b * 64 + g * 16) * 4096;
    int t = threadIdx.x;
    if (t < 288) Tl[t] = Tt[t];

    // ---- load x halo tile into registers: 648 tasks = 324 px x 2 ch-halves ----
    float r[2][8];
    bool okv[2];
    #pragma unroll
    for (int i = 0; i < 2; ++i) {
        okv[i] = false;
        int idx = t + i * 512;
        if (idx < 648) {
            int half = idx >= 324 ? 1 : 0;
            int pix = idx - half * 324;
            int ly = pix / 18, lx = pix - ly * 18;
            int gh = th0 + ly - 1, gw = tw0 + lx - 1;
            bool ok = (gh >= 0 && gh < NH && gw >= 0 && gw < NW);
            okv[i] = ok;
            const float* s = xg + (size_t)(half * 8) * 4096 + gh * 64 + gw;
            #pragma unroll
            for (int j = 0; j < 8; ++j)
                r[i][j] = ok ? s[(size_t)j * 4096] : 0.f;
        }
    }

    int wv = t >> 6;
    int lane = t & 63;
    int lo = lane & 31, hi = lane >> 5;
    int py = 2 * wv + (lo >> 4), px = lo & 15;

    f32x16 acc = {};

    // ---- 4 K-phases: 0=silu, 1=xn, 2=P2, 3=P3 ----
    #pragma unroll
    for (int p = 0; p < 4; ++p) {
        // stage this phase's transform (all b128 writes)
        #pragma unroll
        for (int i = 0; i < 2; ++i) {
            int idx = t + i * 512;
            if (idx < 648) {
                int half = idx >= 324 ? 1 : 0;
                int pix = idx - half * 324;
                bf16x8 v;
                #pragma unroll
                for (int j = 0; j < 8; ++j) {
                    float val = r[i][j];
                    float o;
                    if (p == 0) {
                        o = silu(val);               // silu(0)=0: OOB safe
                    } else {
                        float xn = (val - xmin) * inv - 1.f;
                        if (p == 1) o = xn;
                        else {
                            float x2 = xn * xn;
                            o = (p == 2) ? (1.5f * x2 - 0.5f) : ((2.5f * x2 - 1.5f) * xn);
                        }
                        o = okv[i] ? o : 0.f;
                    }
                    v[j] = (short)tobf(o);
                }
                *(bf16x8*)&augp[(half * 324 + pix) * 8] = v;
            }
        }
        // copy this phase's weight slice: 9216 B = 576 uint4
        {
            const uint4* srcw = (const uint4*)(wpk + p * 4608);
            uint4* dstw = (uint4*)wlp;
            dstw[t] = srcw[t];
            int i2 = t + 512;
            if (i2 < 576) dstw[i2] = srcw[i2];
        }
        __syncthreads();

        // 9 MFMAs: one per tap (K=16 = h0/h1 halves of this phase)
        #pragma unroll
        for (int tap = 0; tap < 9; ++tap) {
            const int ky = tap / 3, kx = tap % 3;
            const int hp = (py + ky) * 18 + (px + kx);
            bf16x8 Af = *(const bf16x8*)&wlp[((tap * 2 + hi) * 32 + lo) * 8];
            bf16x8 Bf = *(const bf16x8*)&augp[(hi * 324 + hp) * 8];
            acc = __builtin_amdgcn_mfma_f32_32x32x16_bf16(Af, Bf, acc, 0, 0, 0);
        }
        __syncthreads();
    }

    // ---- epilogue: ones-term + stores (bf16 scratch if available) ----
    int h = th0 + py, wc = tw0 + px;
    int ey = (h == 0) ? 0 : ((h == NH - 1) ? 2 : 1);
    int ex = (wc == 0) ? 0 : ((wc == NW - 1) ? 2 : 1);
    int et = ey * 3 + ex;
    size_t obase = ((size_t)b * 128 + g * 32) * 4096 + (size_t)h * 64 + wc;
    if (yscr) {
        #pragma unroll
        for (int rr = 0; rr < 16; ++rr) {
            int oc = (rr & 3) + 8 * (rr >> 2) + 4 * hi;
            yscr[obase + (size_t)oc * 4096] = tobf(acc[rr] + Tl[oc * 9 + et]);
        }
    } else {
        #pragma unroll
        for (int rr = 0; rr < 16; ++rr) {
            int oc = (rr & 3) + 8 * (rr >> 2) + 4 * hi;
            out[obase + (size_t)oc * 4096] = acc[rr] + Tl[oc * 9 + et];
        }
    }
}

// ---- norm from bf16 scratch: read 67MB, write 134MB ----
__global__ __launch_bounds__(256) void norm_bf16_kernel(const unsigned short* __restrict__ yscr,
                                                        float* __restrict__ out) {
    int plane = blockIdx.x;      // b*128 + ch
    const u16x8* p = (const u16x8*)(yscr + (size_t)plane * 4096);
    int t = threadIdx.x;
    float v[2][8];
    float s = 0.f, s2 = 0.f;
    #pragma unroll
    for (int k = 0; k < 2; ++k) {
        u16x8 u = p[t + k * 256];
        #pragma unroll
        for (int j = 0; j < 8; ++j) {
            float f = __uint_as_float((unsigned)u[j] << 16);
            v[k][j] = f;
            s += f;
            s2 += f * f;
        }
    }
    #pragma unroll
    for (int off = 32; off; off >>= 1) {
        s  += __shfl_xor(s, off);
        s2 += __shfl_xor(s2, off);
    }
    __shared__ float ss[4], ss2[4];
    int wid = t >> 6, lane = t & 63;
    if (lane == 0) { ss[wid] = s; ss2[wid] = s2; }
    __syncthreads();
    s  = ss[0] + ss[1] + ss[2] + ss[3];
    s2 = ss2[0] + ss2[1] + ss2[2] + ss2[3];
    float mean = s * (1.f / 4096.f);
    float var  = fmaxf(s2 * (1.f / 4096.f) - mean * mean, 0.f);
    float istd = rsqrtf(var + 1e-5f);
    float4* o = (float4*)(out + (size_t)plane * 4096);
    #pragma unroll
    for (int k = 0; k < 2; ++k) {
        float4 a, bq;
        a.x = silu((v[k][0] - mean) * istd);
        a.y = silu((v[k][1] - mean) * istd);
        a.z = silu((v[k][2] - mean) * istd);
        a.w = silu((v[k][3] - mean) * istd);
        bq.x = silu((v[k][4] - mean) * istd);
        bq.y = silu((v[k][5] - mean) * istd);
        bq.z = silu((v[k][6] - mean) * istd);
        bq.w = silu((v[k][7] - mean) * istd);
        o[(t + k * 256) * 2]     = a;
        o[(t + k * 256) * 2 + 1] = bq;
    }
}

// ---- fallback: in-place f32 norm ----
__global__ __launch_bounds__(256) void norm_kernel(float* __restrict__ out) {
    int plane = blockIdx.x;      // b*128 + ch
    float4* p = (float4*)(out + (size_t)plane * 4096);
    int t = threadIdx.x;
    float4 v[4];
    float s = 0.f, s2 = 0.f;
    #pragma unroll
    for (int k = 0; k < 4; ++k) {
        v[k] = p[t + k * 256];
        s  += v[k].x + v[k].y + v[k].z + v[k].w;
        s2 += v[k].x * v[k].x + v[k].y * v[k].y + v[k].z * v[k].z + v[k].w * v[k].w;
    }
    #pragma unroll
    for (int off = 32; off; off >>= 1) {
        s  += __shfl_xor(s, off);
        s2 += __shfl_xor(s2, off);
    }
    __shared__ float ss[4], ss2[4];
    int wid = t >> 6, lane = t & 63;
    if (lane == 0) { ss[wid] = s; ss2[wid] = s2; }
    __syncthreads();
    s  = ss[0] + ss[1] + ss[2] + ss[3];
    s2 = ss2[0] + ss2[1] + ss2[2] + ss2[3];
    float mean = s * (1.f / 4096.f);
    float var  = fmaxf(s2 * (1.f / 4096.f) - mean * mean, 0.f);
    float istd = rsqrtf(var + 1e-5f);
    #pragma unroll
    for (int k = 0; k < 4; ++k) {
        float4 o;
        o.x = (v[k].x - mean) * istd; o.x = silu(o.x);
        o.y = (v[k].y - mean) * istd; o.y = silu(o.y);
        o.z = (v[k].z - mean) * istd; o.z = silu(o.z);
        o.w = (v[k].w - mean) * istd; o.w = silu(o.w);
        p[t + k * 256] = o;
    }
}

extern "C" void kernel_launch(void* const* d_in, const int* in_sizes, int n_in,
                              void* d_out, int out_size, void* d_ws, size_t ws_size,
                              hipStream_t stream) {
    const float* x = (const float*)d_in[0];
    const float* w = (const float*)d_in[1];
    float* out = (float*)d_out;
    float* wsf = (float*)d_ws;                                        // 8 floats
    float* pmm = (float*)((char*)d_ws + 64);                          // 8192 floats
    unsigned short* wpk = (unsigned short*)((char*)d_ws + 64 + 32768);// 18432 bf16
    float* Tt = (float*)((char*)d_ws + 64 + 32768 + 36864);           // 288 floats

    const size_t YSCR_OFF = 131072;
    const size_t YSCR_BYTES = (size_t)64 * 128 * 4096 * 2;            // 67.1 MB
    unsigned short* yscr = (ws_size >= YSCR_OFF + YSCR_BYTES)
                         ? (unsigned short*)((char*)d_ws + YSCR_OFF) : nullptr;

    hipLaunchKernelGGL(minmax_kernel, dim3(NB * 64), dim3(256), 0, stream, x, pmm);
    hipLaunchKernelGGL(reduce_repack_kernel, dim3(77), dim3(256), 0, stream, pmm, w, wsf, wpk, Tt);
    hipLaunchKernelGGL(conv_mfma_kernel, dim3(4096), dim3(512), 0, stream, x, wsf, wpk, Tt, out, yscr);
    if (yscr)
        hipLaunchKernelGGL(norm_bf16_kernel, dim3(NB * 128), dim3(256), 0, stream, yscr, out);
    else
        hipLaunchKernelGGL(norm_kernel, dim3(NB * 128), dim3(256), 0, stream, out);
}

// Round 12
// 132.351 us; speedup vs baseline: 1.3649x; 1.0065x over previous
//
#include <hip/hip_runtime.h>
#include <hip/hip_bf16.h>

// SimpleMetaConvKALN: x (64,64,64,64) f32, w (32,80,3,3) f32 -> out (64,128,64,64) f32
// y = conv3x3(aug(x), w) per group; instance-norm per (b,oc); silu.
// K=64 (ones-block analytic via T[oc][ey][ex]).
// K in 4 phases (silu/xn/P2/P3): x tile in registers; FULL weight table (36KB)
// staged in LDS once per block; per-phase aug 10.4KB -> 48.4KB LDS, 3 blocks/CU.
// y transits conv->norm as bf16 scratch (ws-gated, f32 fallback).

#define NB 64
#define NH 64
#define NW 64

typedef __attribute__((ext_vector_type(8)))  short bf16x8;
typedef __attribute__((ext_vector_type(8)))  unsigned short u16x8;
typedef __attribute__((ext_vector_type(16))) float f32x16;

__device__ __forceinline__ float silu(float v) {
    return v / (1.0f + __expf(-v));
}
__device__ __forceinline__ unsigned short tobf(float f) {   // native cvt (RNE)
    union { __hip_bfloat16 h; unsigned short u; } cv;
    cv.h = __float2bfloat16(f);
    return cv.u;
}

// ---- per-plane min/max (no atomics) ----
__global__ __launch_bounds__(256) void minmax_kernel(const float* __restrict__ x,
                                                     float* __restrict__ pmm) {
    int plane = blockIdx.x;          // b*64 + ch
    const float4* p = (const float4*)(x + (size_t)plane * 4096);
    int t = threadIdx.x;
    float mn = 3.4e38f, mx = -3.4e38f;
    #pragma unroll
    for (int k = 0; k < 4; ++k) {
        float4 v = p[t + k * 256];
        mn = fminf(mn, fminf(fminf(v.x, v.y), fminf(v.z, v.w)));
        mx = fmaxf(mx, fmaxf(fmaxf(v.x, v.y), fmaxf(v.z, v.w)));
    }
    #pragma unroll
    for (int off = 32; off; off >>= 1) {
        mn = fminf(mn, __shfl_xor(mn, off));
        mx = fmaxf(mx, __shfl_xor(mx, off));
    }
    __shared__ float smn[4], smx[4];
    int wid = t >> 6, lane = t & 63;
    if (lane == 0) { smn[wid] = mn; smx[wid] = mx; }
    __syncthreads();
    if (t == 0) {
        mn = fminf(fminf(smn[0], smn[1]), fminf(smn[2], smn[3]));
        mx = fmaxf(fmaxf(smx[0], smx[1]), fmaxf(smx[2], smx[3]));
        pmm[plane * 2]     = mn;
        pmm[plane * 2 + 1] = mx;
    }
}

// blk 0-3: reduce pmm -> wsf[g]
// blk 4-75: repack w -> bf16 phase-major [p][tap][h][oc][8]
// blk 76: ones-channel analytic table T[oc][ey][ex]
__global__ __launch_bounds__(256) void reduce_repack_kernel(const float* __restrict__ pmm,
                                                            const float* __restrict__ w,
                                                            float* __restrict__ wsf,
                                                            unsigned short* __restrict__ wpk,
                                                            float* __restrict__ Tt) {
    int blk = blockIdx.x;
    int t = threadIdx.x;
    if (blk < 4) {
        int g = blk;
        float mn = 3.4e38f, mx = -3.4e38f;
        #pragma unroll
        for (int j = 0; j < 4; ++j) {
            int p = t + j * 256;             // 0..1023
            int b = p >> 4, c = p & 15;
            int plane = b * 64 + g * 16 + c;
            mn = fminf(mn, pmm[plane * 2]);
            mx = fmaxf(mx, pmm[plane * 2 + 1]);
        }
        #pragma unroll
        for (int off = 32; off; off >>= 1) {
            mn = fminf(mn, __shfl_xor(mn, off));
            mx = fmaxf(mx, __shfl_xor(mx, off));
        }
        __shared__ float smn[4], smx[4];
        int wid = t >> 6, lane = t & 63;
        if (lane == 0) { smn[wid] = mn; smx[wid] = mx; }
        __syncthreads();
        if (t == 0) {
            mn = fminf(fminf(smn[0], smn[1]), fminf(smn[2], smn[3]));
            mx = fmaxf(fmaxf(smx[0], smx[1]), fmaxf(smx[2], smx[3]));
            wsf[g * 2]     = mn;
            wsf[g * 2 + 1] = mx;
        }
    } else if (blk < 76) {
        int idx = (blk - 4) * 256 + t;       // < 18432 = 4*9*2*32*8
        int p   = idx / 4608;                // phase
        int r1  = idx - p * 4608;
        int tap = r1 / 512;
        int r2  = r1 - tap * 512;
        int h   = r2 >> 8;                   // k-half within phase
        int oc  = (r2 >> 3) & 31;
        int j   = r2 & 7;
        int k   = p * 16 + h * 8 + j;
        int orig = (k < 16) ? k : (k + 16);  // skip ones block (orig 16..31)
        wpk[idx] = tobf(w[oc * 720 + orig * 9 + tap]);
    } else {
        for (int i = t; i < 288; i += 256) {
            int oc = i / 9, ty = i - oc * 9;
            int ey = ty / 3, ex = ty - ey * 3;
            int ky0 = (ey == 0) ? 1 : 0, ky1 = (ey == 2) ? 1 : 2;
            int kx0 = (ex == 0) ? 1 : 0, kx1 = (ex == 2) ? 1 : 2;
            float s = 0.f;
            for (int c = 0; c < 16; ++c)
                for (int ky = ky0; ky <= ky1; ++ky)
                    for (int kx = kx0; kx <= kx1; ++kx)
                        s += w[oc * 720 + (16 + c) * 9 + ky * 3 + kx];
            Tt[i] = s;
        }
    }
}

__global__ __launch_bounds__(512, 6) void conv_mfma_kernel(const float* __restrict__ x,
                                                           const float* __restrict__ wsf,
                                                           const unsigned short* __restrict__ wpk,
                                                           const float* __restrict__ Tt,
                                                           float* __restrict__ out,
                                                           unsigned short* __restrict__ yscr) {
    __shared__ unsigned short wl[18432];    // [p][tap][h][oc][8]  36864 B (all phases)
    __shared__ unsigned short augp[5184];   // [h][pix 0..323][8]  10368 B
    __shared__ float Tl[288];               // 1152 B

    // XCD swizzle: consecutive work-chunks of 512 land on one XCD
    int flat = blockIdx.x;                       // 0..4095
    int f = ((flat & 7) << 9) | (flat >> 3);     // bijective
    int tile = f & 15;
    int bg = f >> 4;
    int b = bg & 63;
    int g = bg >> 6;
    int th0 = (tile >> 2) * 16, tw0 = (tile & 3) * 16;

    float xmin = wsf[g * 2];
    float xmax = wsf[g * 2 + 1];
    float inv = 2.0f / (xmax - xmin);

    const float* xg = x + ((size_t)b * 64 + g * 16) * 4096;
    int t = threadIdx.x;

    // ---- full weight table: global -> LDS once (2304 uint4) ----
    {
        const uint4* srcw = (const uint4*)wpk;
        uint4* dstw = (uint4*)wl;
        #pragma unroll
        for (int i = 0; i < 5; ++i) {
            int idx = t + i * 512;
            if (idx < 2304) dstw[idx] = srcw[idx];
        }
    }
    if (t < 288) Tl[t] = Tt[t];

    // ---- load x halo tile into registers: 648 tasks = 324 px x 2 ch-halves ----
    float r[2][8];
    bool okv[2];
    #pragma unroll
    for (int i = 0; i < 2; ++i) {
        okv[i] = false;
        int idx = t + i * 512;
        if (idx < 648) {
            int half = idx >= 324 ? 1 : 0;
            int pix = idx - half * 324;
            int ly = pix / 18, lx = pix - ly * 18;
            int gh = th0 + ly - 1, gw = tw0 + lx - 1;
            bool ok = (gh >= 0 && gh < NH && gw >= 0 && gw < NW);
            okv[i] = ok;
            const float* s = xg + (size_t)(half * 8) * 4096 + gh * 64 + gw;
            #pragma unroll
            for (int j = 0; j < 8; ++j)
                r[i][j] = ok ? s[(size_t)j * 4096] : 0.f;
        }
    }

    int wv = t >> 6;
    int lane = t & 63;
    int lo = lane & 31, hi = lane >> 5;
    int py = 2 * wv + (lo >> 4), px = lo & 15;

    f32x16 acc = {};

    // ---- 4 K-phases: 0=silu, 1=xn, 2=P2, 3=P3 ----
    #pragma unroll
    for (int p = 0; p < 4; ++p) {
        // stage this phase's transform (all b128 writes, pure reg->VALU->LDS)
        #pragma unroll
        for (int i = 0; i < 2; ++i) {
            int idx = t + i * 512;
            if (idx < 648) {
                int half = idx >= 324 ? 1 : 0;
                int pix = idx - half * 324;
                bf16x8 v;
                #pragma unroll
                for (int j = 0; j < 8; ++j) {
                    float val = r[i][j];
                    float o;
                    if (p == 0) {
                        o = silu(val);               // silu(0)=0: OOB safe
                    } else {
                        float xn = (val - xmin) * inv - 1.f;
                        if (p == 1) o = xn;
                        else {
                            float x2 = xn * xn;
                            o = (p == 2) ? (1.5f * x2 - 0.5f) : ((2.5f * x2 - 1.5f) * xn);
                        }
                        o = okv[i] ? o : 0.f;
                    }
                    v[j] = (short)tobf(o);
                }
                *(bf16x8*)&augp[(half * 324 + pix) * 8] = v;
            }
        }
        __syncthreads();

        // 9 MFMAs: one per tap (K=16 = h0/h1 halves of this phase)
        #pragma unroll
        for (int tap = 0; tap < 9; ++tap) {
            const int ky = tap / 3, kx = tap % 3;
            const int hp = (py + ky) * 18 + (px + kx);
            bf16x8 Af = *(const bf16x8*)&wl[(((p * 9 + tap) * 2 + hi) * 32 + lo) * 8];
            bf16x8 Bf = *(const bf16x8*)&augp[(hi * 324 + hp) * 8];
            acc = __builtin_amdgcn_mfma_f32_32x32x16_bf16(Af, Bf, acc, 0, 0, 0);
        }
        __syncthreads();
    }

    // ---- epilogue: ones-term + stores (bf16 scratch if available) ----
    int h = th0 + py, wc = tw0 + px;
    int ey = (h == 0) ? 0 : ((h == NH - 1) ? 2 : 1);
    int ex = (wc == 0) ? 0 : ((wc == NW - 1) ? 2 : 1);
    int et = ey * 3 + ex;
    size_t obase = ((size_t)b * 128 + g * 32) * 4096 + (size_t)h * 64 + wc;
    if (yscr) {
        #pragma unroll
        for (int rr = 0; rr < 16; ++rr) {
            int oc = (rr & 3) + 8 * (rr >> 2) + 4 * hi;
            yscr[obase + (size_t)oc * 4096] = tobf(acc[rr] + Tl[oc * 9 + et]);
        }
    } else {
        #pragma unroll
        for (int rr = 0; rr < 16; ++rr) {
            int oc = (rr & 3) + 8 * (rr >> 2) + 4 * hi;
            out[obase + (size_t)oc * 4096] = acc[rr] + Tl[oc * 9 + et];
        }
    }
}

// ---- norm from bf16 scratch: read 67MB, write 134MB ----
__global__ __launch_bounds__(256) void norm_bf16_kernel(const unsigned short* __restrict__ yscr,
                                                        float* __restrict__ out) {
    int plane = blockIdx.x;      // b*128 + ch
    const u16x8* p = (const u16x8*)(yscr + (size_t)plane * 4096);
    int t = threadIdx.x;
    float v[2][8];
    float s = 0.f, s2 = 0.f;
    #pragma unroll
    for (int k = 0; k < 2; ++k) {
        u16x8 u = p[t + k * 256];
        #pragma unroll
        for (int j = 0; j < 8; ++j) {
            float f = __uint_as_float((unsigned)u[j] << 16);
            v[k][j] = f;
            s += f;
            s2 += f * f;
        }
    }
    #pragma unroll
    for (int off = 32; off; off >>= 1) {
        s  += __shfl_xor(s, off);
        s2 += __shfl_xor(s2, off);
    }
    __shared__ float ss[4], ss2[4];
    int wid = t >> 6, lane = t & 63;
    if (lane == 0) { ss[wid] = s; ss2[wid] = s2; }
    __syncthreads();
    s  = ss[0] + ss[1] + ss[2] + ss[3];
    s2 = ss2[0] + ss2[1] + ss2[2] + ss2[3];
    float mean = s * (1.f / 4096.f);
    float var  = fmaxf(s2 * (1.f / 4096.f) - mean * mean, 0.f);
    float istd = rsqrtf(var + 1e-5f);
    float4* o = (float4*)(out + (size_t)plane * 4096);
    #pragma unroll
    for (int k = 0; k < 2; ++k) {
        float4 a, bq;
        a.x = silu((v[k][0] - mean) * istd);
        a.y = silu((v[k][1] - mean) * istd);
        a.z = silu((v[k][2] - mean) * istd);
        a.w = silu((v[k][3] - mean) * istd);
        bq.x = silu((v[k][4] - mean) * istd);
        bq.y = silu((v[k][5] - mean) * istd);
        bq.z = silu((v[k][6] - mean) * istd);
        bq.w = silu((v[k][7] - mean) * istd);
        o[(t + k * 256) * 2]     = a;
        o[(t + k * 256) * 2 + 1] = bq;
    }
}

// ---- fallback: in-place f32 norm ----
__global__ __launch_bounds__(256) void norm_kernel(float* __restrict__ out) {
    int plane = blockIdx.x;      // b*128 + ch
    float4* p = (float4*)(out + (size_t)plane * 4096);
    int t = threadIdx.x;
    float4 v[4];
    float s = 0.f, s2 = 0.f;
    #pragma unroll
    for (int k = 0; k < 4; ++k) {
        v[k] = p[t + k * 256];
        s  += v[k].x + v[k].y + v[k].z + v[k].w;
        s2 += v[k].x * v[k].x + v[k].y * v[k].y + v[k].z * v[k].z + v[k].w * v[k].w;
    }
    #pragma unroll
    for (int off = 32; off; off >>= 1) {
        s  += __shfl_xor(s, off);
        s2 += __shfl_xor(s2, off);
    }
    __shared__ float ss[4], ss2[4];
    int wid = t >> 6, lane = t & 63;
    if (lane == 0) { ss[wid] = s; ss2[wid] = s2; }
    __syncthreads();
    s  = ss[0] + ss[1] + ss[2] + ss[3];
    s2 = ss2[0] + ss2[1] + ss2[2] + ss2[3];
    float mean = s * (1.f / 4096.f);
    float var  = fmaxf(s2 * (1.f / 4096.f) - mean * mean, 0.f);
    float istd = rsqrtf(var + 1e-5f);
    #pragma unroll
    for (int k = 0; k < 4; ++k) {
        float4 o;
        o.x = (v[k].x - mean) * istd; o.x = silu(o.x);
        o.y = (v[k].y - mean) * istd; o.y = silu(o.y);
        o.z = (v[k].z - mean) * istd; o.z = silu(o.z);
        o.w = (v[k].w - mean) * istd; o.w = silu(o.w);
        p[t + k * 256] = o;
    }
}

extern "C" void kernel_launch(void* const* d_in, const int* in_sizes, int n_in,
                              void* d_out, int out_size, void* d_ws, size_t ws_size,
                              hipStream_t stream) {
    const float* x = (const float*)d_in[0];
    const float* w = (const float*)d_in[1];
    float* out = (float*)d_out;
    float* wsf = (float*)d_ws;                                        // 8 floats
    float* pmm = (float*)((char*)d_ws + 64);                          // 8192 floats
    unsigned short* wpk = (unsigned short*)((char*)d_ws + 64 + 32768);// 18432 bf16
    float* Tt = (float*)((char*)d_ws + 64 + 32768 + 36864);           // 288 floats

    const size_t YSCR_OFF = 131072;
    const size_t YSCR_BYTES = (size_t)64 * 128 * 4096 * 2;            // 67.1 MB
    unsigned short* yscr = (ws_size >= YSCR_OFF + YSCR_BYTES)
                         ? (unsigned short*)((char*)d_ws + YSCR_OFF) : nullptr;

    hipLaunchKernelGGL(minmax_kernel, dim3(NB * 64), dim3(256), 0, stream, x, pmm);
    hipLaunchKernelGGL(reduce_repack_kernel, dim3(77), dim3(256), 0, stream, pmm, w, wsf, wpk, Tt);
    hipLaunchKernelGGL(conv_mfma_kernel, dim3(4096), dim3(512), 0, stream, x, wsf, wpk, Tt, out, yscr);
    if (yscr)
        hipLaunchKernelGGL(norm_bf16_kernel, dim3(NB * 128), dim3(256), 0, stream, yscr, out);
    else
        hipLaunchKernelGGL(norm_kernel, dim3(NB * 128), dim3(256), 0, stream, out);
}